// Round 13
// baseline (247.573 us; speedup 1.0000x reference)
//
#include <hip/hip_runtime.h>
#include <stdint.h>

#define BDIM 4
#define TDIM 4096
#define CDIM 1024
#define MDIM (BDIM * TDIM) // 16384
#define SSEG 64            // segments along T
#define LSEG 64            // steps per segment
#define NCH  (BDIM * CDIM) // 4096 channels

#define GK2  2048          // K row stride in bytes (bf16)
#define NK32 32            // K-tiles of 32

typedef __attribute__((ext_vector_type(8))) short bf16x8;
typedef __attribute__((ext_vector_type(4))) float f32x4;

__device__ __forceinline__ unsigned short f2bf(float f) {
    unsigned u = __builtin_bit_cast(unsigned, f);
    u = u + 0x7fffu + ((u >> 16) & 1u); // RNE
    return (unsigned short)(u >> 16);
}
__device__ __forceinline__ float bf2f(unsigned short h) {
    unsigned u = ((unsigned)h) << 16;
    return __builtin_bit_cast(float, u);
}

typedef __attribute__((address_space(1))) const unsigned int g_u32;
typedef __attribute__((address_space(3))) unsigned int l_u32;
__device__ __forceinline__ void gload_lds16(const void* g, void* l) {
    __builtin_amdgcn_global_load_lds((g_u32*)g, (l_u32*)l, 16, 0, 0);
}

// ---------------- all fp32 -> bf16 casts in ONE launch ----------------
__global__ void castall(const float* __restrict__ x,
                        const float* __restrict__ kw, const float* __restrict__ vw,
                        const float* __restrict__ rw, const float* __restrict__ ow,
                        unsigned short* __restrict__ xb,
                        unsigned short* __restrict__ wf, unsigned short* __restrict__ owb) {
    int i = blockIdx.x * 256 + threadIdx.x;
    const float* s;
    unsigned short* d;
    int j;
    if (i < 4194304) {                       // x
        s = x; d = xb; j = i;
    } else {
        int k = i - 4194304;
        int m = k >> 18; j = k & 262143;     // which weight
        s = (m == 0) ? kw : (m == 1) ? vw : (m == 2) ? rw : ow;
        d = (m < 3) ? (wf + (size_t)m * 1048576) : owb;
    }
    float4 f = ((const float4*)s)[j];
    ushort4 o;
    o.x = f2bf(f.x); o.y = f2bf(f.y); o.z = f2bf(f.z); o.w = f2bf(f.w);
    ((ushort4*)d)[j] = o;
}

// ---------------- 128x128 bf16 GEMM, BK=32, 4 blocks/CU (m97 structure) ----
// 256 threads = 4 waves (2x2), 16x16x32 MFMA, 32 KiB LDS (2 buf x A+B 8KB),
// stage-ahead double buffer: STAGE(t+1) at iter top, reads+MFMA of tile t,
// one vmcnt(0)+s_barrier per iter. Occupancy: __launch_bounds__(256,4) +
// 32 KiB LDS -> 4 blocks/CU; cross-block co-scheduling (m114) hides the
// staging latency that the 1-block/CU 256x256 variants could not.
// L2 swizzle: each XCD owns a disjoint 16-panel A slice (4 MB = L2 size),
// nt-fast within XCD. MODE 0: QKV epilogue (K/V bf16, R sigmoid bf16).
// MODE 1: fp32 store.
template <int MODE, int NT>
__global__ __launch_bounds__(256, 4) void gemm128(
    const unsigned short* __restrict__ A,
    const unsigned short* __restrict__ Bw,
    unsigned short* __restrict__ oK, unsigned short* __restrict__ oV,
    unsigned short* __restrict__ oR, float* __restrict__ oF)
{
    __shared__ char sh[32768];               // [2 buf][A 8KB | B 8KB]

    const int tid  = threadIdx.x;
    const int wave = tid >> 6;
    const int lane = tid & 63;
    const int wm   = wave >> 1;      // 0..1 (M half)
    const int wn   = wave & 1;       // 0..1 (N half)
    const int lrow = lane & 15;
    const int koct = lane >> 4;      // 0..3

    // per-thread frag read offsets (tile stored [128 rows][64 B])
    const int ao = (wm * 64 + lrow) * 64 + koct * 16;
    const int bo = (wn * 64 + lrow) * 64 + koct * 16;

    // per-thread stage offsets: 2 chunks of 16B per matrix per iter
    const int r0  = tid >> 2;                // row of chunk 0 (0..63)
    const int c0  = (tid & 3) * 16;          // byte col within 64B row
    const int s0  = r0 * GK2 + c0;           // global byte offset (row-major)
    const int s1  = (r0 + 64) * GK2 + c0;
    const int d0  = tid * 16;                // LDS dest chunk 0
    const int d1  = 4096 + tid * 16;         // LDS dest chunk 1

    // L2-locality XCD swizzle: grid = 8 * 16 * NT blocks
    const int bid = blockIdx.x;
    const int xcd = bid & 7;
    const int idx = bid >> 3;
    const int mt  = xcd * 16 + idx / NT;     // disjoint 16-panel A slice/XCD
    const int nt  = idx % NT;                // nt-fast: A panel L2-reused
    const size_t row0 = (size_t)mt * 128;
    const size_t col0 = (size_t)nt * 128;

    const char* gA = (const char*)A  + row0 * GK2;
    const char* gB = (const char*)Bw + col0 * GK2;

    // stage tile tt (A and B, 4 gloads/thread) into buffer tt&1
    auto stage = [&](int tt) {
        if (tt >= NK32) return;
        char* lb = sh + (tt & 1) * 8192;
        const char* ga = gA + tt * 64;
        const char* gb = gB + tt * 64;
        gload_lds16(ga + s0, lb + d0);
        gload_lds16(ga + s1, lb + d1);
        gload_lds16(gb + s0, lb + 16384 + d0);
        gload_lds16(gb + s1, lb + 16384 + d1);
    };

    // prologue
    stage(0);
    asm volatile("s_waitcnt vmcnt(0)" ::: "memory");
    __builtin_amdgcn_s_barrier();

    f32x4 acc[4][4] = {};
    bf16x8 af[4], bf_[4];

    for (int t = 0; t < NK32; ++t) {
        stage(t + 1);                        // prefetch next tile (other buf)
        const char* ab = sh + (t & 1) * 8192 + ao;
        const char* bb = sh + (t & 1) * 8192 + 16384 + bo;
#pragma unroll
        for (int mi = 0; mi < 4; ++mi) af[mi]  = *(const bf16x8*)(ab + mi * 1024);
#pragma unroll
        for (int ni = 0; ni < 4; ++ni) bf_[ni] = *(const bf16x8*)(bb + ni * 1024);
        __builtin_amdgcn_s_setprio(1);
#pragma unroll
        for (int mi = 0; mi < 4; ++mi)
#pragma unroll
            for (int ni = 0; ni < 4; ++ni)
                acc[mi][ni] = __builtin_amdgcn_mfma_f32_16x16x32_bf16(af[mi], bf_[ni], acc[mi][ni], 0, 0, 0);
        __builtin_amdgcn_s_setprio(0);
        asm volatile("s_waitcnt vmcnt(0)" ::: "memory");  // next tile resident
        __builtin_amdgcn_s_barrier();
    }

    // ---- epilogue: C/D frag layout col=lane&15, row=(lane>>4)*4+j
    const int crow = (lane >> 4) * 4;
    const int ccol = lane & 15;
    if (MODE == 1) {
#pragma unroll
        for (int mi = 0; mi < 4; ++mi)
#pragma unroll
            for (int ni = 0; ni < 4; ++ni) {
                size_t gr = row0 + wm * 64 + mi * 16 + crow;
                size_t gc = col0 + wn * 64 + ni * 16 + ccol;
#pragma unroll
                for (int j = 0; j < 4; ++j)
                    oF[(gr + j) * 1024 + gc] = acc[mi][ni][j];
            }
    } else {
        const int region = nt >> 3;  // 0=K, 1=V, 2=R  (NT=24: 8 nt per region)
        unsigned short* dst = (region == 0) ? oK : ((region == 1) ? oV : oR);
        const size_t cb0 = (size_t)(nt & 7) * 128;
#pragma unroll
        for (int mi = 0; mi < 4; ++mi)
#pragma unroll
            for (int ni = 0; ni < 4; ++ni) {
                size_t gr = row0 + wm * 64 + mi * 16 + crow;
                size_t gc = cb0 + wn * 64 + ni * 16 + ccol;
#pragma unroll
                for (int j = 0; j < 4; ++j) {
                    float val = acc[mi][ni][j];
                    if (region == 2) val = 1.0f / (1.0f + __expf(-val));
                    dst[(gr + j) * 1024 + gc] = f2bf(val);
                }
            }
    }
}

// ---------------- WKV segmented scan (bf16 k,v,r) ----------------
__global__ __launch_bounds__(256) void wkv_phase1(
    const unsigned short* __restrict__ kf, const unsigned short* __restrict__ vf,
    const float* __restrict__ td,
    float* __restrict__ segA, float* __restrict__ segB, float* __restrict__ segP)
{
    const int tid  = blockIdx.x * 256 + threadIdx.x;
    const int lane = tid & 63;
    const int wg   = tid >> 6;
    const int cg   = wg & 63;
    const int s    = wg >> 6;
    const int q    = cg * 64 + lane;
    const int b    = q >> 10;
    const int c    = q & (CDIM - 1);

    const float w = __expf(td[c]);

    float aa = 0.0f, bb = 0.0f, pp = -1e38f;
    size_t idx = (size_t)b * TDIM * CDIM + (size_t)(s * LSEG) * CDIM + c;
#pragma unroll 4
    for (int i = 0; i < LSEG; ++i, idx += CDIM) {
        float kt = bf2f(kf[idx]);
        float vt = bf2f(vf[idx]);
        float ww2 = pp - w;
        float p2  = fmaxf(ww2, kt);
        float e1  = __expf(ww2 - p2);
        float e2  = __expf(kt - p2);
        aa = e1 * aa + e2 * vt;
        bb = e1 * bb + e2;
        pp = p2;
    }
    segA[s * NCH + q] = aa;
    segB[s * NCH + q] = bb;
    segP[s * NCH + q] = pp;
}

__global__ __launch_bounds__(256) void wkv_phase2(
    const float* __restrict__ segA, const float* __restrict__ segB, const float* __restrict__ segP,
    const float* __restrict__ td,
    const float* __restrict__ aa0, const float* __restrict__ bb0, const float* __restrict__ pp0,
    float* __restrict__ preA, float* __restrict__ preB, float* __restrict__ preP,
    float* __restrict__ stout)
{
    const int tid = blockIdx.x * 256 + threadIdx.x;   // 0..NCH-1
    const int c = tid & (CDIM - 1);
    const float w  = __expf(td[c]);
    const float Lw = (float)LSEG * w;

    float aa = aa0[tid], bb = bb0[tid], pp = pp0[tid];
    for (int s = 0; s < SSEG; ++s) {
        preA[s * NCH + tid] = aa;
        preB[s * NCH + tid] = bb;
        preP[s * NCH + tid] = pp;
        float al = segA[s * NCH + tid];
        float bl = segB[s * NCH + tid];
        float pl = segP[s * NCH + tid];
        float ppd = pp - Lw;
        float p  = fmaxf(ppd, pl);
        float e1 = __expf(ppd - p);
        float e2 = __expf(pl - p);
        aa = e1 * aa + e2 * al;
        bb = e1 * bb + e2 * bl;
        pp = p;
    }
    stout[tid]           = aa;
    stout[NCH + tid]     = bb;
    stout[2 * NCH + tid] = pp;
}

__global__ __launch_bounds__(256) void wkv_phase3(
    const unsigned short* __restrict__ kf, const unsigned short* __restrict__ vf,
    const unsigned short* __restrict__ rb,
    const float* __restrict__ td, const float* __restrict__ tf,
    const float* __restrict__ preA, const float* __restrict__ preB, const float* __restrict__ preP,
    unsigned short* __restrict__ rwkvb)
{
    const int tid  = blockIdx.x * 256 + threadIdx.x;
    const int lane = tid & 63;
    const int wg   = tid >> 6;
    const int cg   = wg & 63;
    const int s    = wg >> 6;
    const int q    = cg * 64 + lane;
    const int b    = q >> 10;
    const int c    = q & (CDIM - 1);

    const float w = __expf(td[c]);
    const float u = tf[c];

    float aa = preA[s * NCH + q];
    float bb = preB[s * NCH + q];
    float pp = preP[s * NCH + q];

    size_t idx = (size_t)b * TDIM * CDIM + (size_t)(s * LSEG) * CDIM + c;
#pragma unroll 4
    for (int i = 0; i < LSEG; ++i, idx += CDIM) {
        float kt = bf2f(kf[idx]);
        float vt = bf2f(vf[idx]);
        float rt = bf2f(rb[idx]);
        float ww = u + kt;
        float p  = fmaxf(pp, ww);
        float e1 = __expf(pp - p);
        float e2 = __expf(ww - p);
        float wkv = (e1 * aa + e2 * vt) / (e1 * bb + e2);
        rwkvb[idx] = f2bf(rt * wkv);
        float ww2 = pp - w;
        float p2  = fmaxf(ww2, kt);
        float e1b = __expf(ww2 - p2);
        float e2b = __expf(kt - p2);
        aa = e1b * aa + e2b * vt;
        bb = e1b * bb + e2b;
        pp = p2;
    }
}

extern "C" void kernel_launch(void* const* d_in, const int* in_sizes, int n_in,
                              void* d_out, int out_size, void* d_ws, size_t ws_size,
                              hipStream_t stream) {
    const float* x   = (const float*)d_in[0];
    const float* kw  = (const float*)d_in[1];
    const float* vw  = (const float*)d_in[2];
    const float* rw  = (const float*)d_in[3];
    const float* ow  = (const float*)d_in[4];
    const float* td  = (const float*)d_in[5];
    const float* tf  = (const float*)d_in[6];
    const float* aa0 = (const float*)d_in[7];
    const float* bb0 = (const float*)d_in[8];
    const float* pp0 = (const float*)d_in[9];
    float* out = (float*)d_out;

    char* ws = (char*)d_ws;
    unsigned short* wf    = (unsigned short*)(ws);               //  6,291,456 B  [3072][1024] bf16
    unsigned short* owb   = (unsigned short*)(ws + 6291456);     //  2,097,152 B
    unsigned short* xb    = (unsigned short*)(ws + 8388608);     // 33,554,432 B
    unsigned short* kfb   = (unsigned short*)(ws + 41943040);    // 33,554,432 B
    unsigned short* vfb   = (unsigned short*)(ws + 75497472);    // 33,554,432 B
    unsigned short* rbb   = (unsigned short*)(ws + 109051904);   // 33,554,432 B
    unsigned short* rwkvb = (unsigned short*)(ws + 142606336);   // 33,554,432 B
    float* segA = (float*)(ws + 176160768);
    float* segB = (float*)(ws + 177209344);
    float* segP = (float*)(ws + 178257920);
    float* preA = (float*)(ws + 179306496);
    float* preB = (float*)(ws + 180355072);
    float* preP = (float*)(ws + 181403648);

    // all casts in one launch
    castall<<<20480, 256, 0, stream>>>(x, kw, vw, rw, ow, xb, wf, owb);

    // fused QKV projection: [16384,1024] x [3072,1024]^T, 128x128 tiles,
    // 8 XCD * 16 mt * 24 nt = 3072 blocks, 4 blocks/CU
    gemm128<0, 24><<<3072, 256, 0, stream>>>(xb, wf, kfb, vfb, rbb, nullptr);

    // segmented WKV scan
    wkv_phase1<<<NCH * SSEG / 256, 256, 0, stream>>>(kfb, vfb, td, segA, segB, segP);
    wkv_phase2<<<NCH / 256, 256, 0, stream>>>(segA, segB, segP, td, aa0, bb0, pp0,
                                              preA, preB, preP, out + (size_t)MDIM * CDIM);
    wkv_phase3<<<NCH * SSEG / 256, 256, 0, stream>>>(kfb, vfb, rbb, td, tf,
                                                     preA, preB, preP, rwkvb);

    // output projection: [16384,1024] x [1024,1024]^T -> fp32 d_out,
    // 8 * 16 * 8 = 1024 blocks
    gemm128<1, 8><<<1024, 256, 0, stream>>>(rwkvb, owb, nullptr, nullptr, nullptr, out);
}

// Round 14
// 240.082 us; speedup vs baseline: 1.0312x; 1.0312x over previous
//
#include <hip/hip_runtime.h>
#include <stdint.h>

#define BDIM 4
#define TDIM 4096
#define CDIM 1024
#define MDIM (BDIM * TDIM) // 16384
#define SSEG 64            // segments along T
#define LSEG 64            // steps per segment
#define NCH  (BDIM * CDIM) // 4096 channels

#define GK2  2048          // K row stride in bytes (bf16)
#define NK32 32            // K-tiles of 32

typedef __attribute__((ext_vector_type(8))) short bf16x8;
typedef __attribute__((ext_vector_type(4))) float f32x4;

__device__ __forceinline__ unsigned short f2bf(float f) {
    unsigned u = __builtin_bit_cast(unsigned, f);
    u = u + 0x7fffu + ((u >> 16) & 1u); // RNE
    return (unsigned short)(u >> 16);
}
__device__ __forceinline__ float bf2f(unsigned short h) {
    unsigned u = ((unsigned)h) << 16;
    return __builtin_bit_cast(float, u);
}

typedef __attribute__((address_space(1))) const unsigned int g_u32;
typedef __attribute__((address_space(3))) unsigned int l_u32;
__device__ __forceinline__ void gload_lds16(const void* g, void* l) {
    __builtin_amdgcn_global_load_lds((g_u32*)g, (l_u32*)l, 16, 0, 0);
}

// ---------------- all fp32 -> bf16 casts in ONE launch ----------------
__global__ void castall(const float* __restrict__ x,
                        const float* __restrict__ kw, const float* __restrict__ vw,
                        const float* __restrict__ rw, const float* __restrict__ ow,
                        unsigned short* __restrict__ xb,
                        unsigned short* __restrict__ wf, unsigned short* __restrict__ owb) {
    int i = blockIdx.x * 256 + threadIdx.x;
    const float* s;
    unsigned short* d;
    int j;
    if (i < 4194304) {                       // x
        s = x; d = xb; j = i;
    } else {
        int k = i - 4194304;
        int m = k >> 18; j = k & 262143;     // which weight
        s = (m == 0) ? kw : (m == 1) ? vw : (m == 2) ? rw : ow;
        d = (m < 3) ? (wf + (size_t)m * 1048576) : owb;
    }
    float4 f = ((const float4*)s)[j];
    ushort4 o;
    o.x = f2bf(f.x); o.y = f2bf(f.y); o.z = f2bf(f.z); o.w = f2bf(f.w);
    ((ushort4*)d)[j] = o;
}

// ---------------- 128x128 bf16 GEMM, BK=32, 3-slot ring, 3 blocks/CU --------
// De-confounded occupancy experiment (round-12 had 12.6M bank conflicts from
// a missing swizzle and vmcnt(0)-per-iter = zero prefetch depth):
//  * XOR swizzle for the [128r x 64B] tile: off = koct*16 ^ (((r>>1)&3)<<4),
//    source pre-swizzled for global_load_lds (both-sides, rule 21).
//  * 3-slot LDS ring (48 KiB): stage(t+2) at iter top, vmcnt(4) at iter end
//    -> tile t+1 resident, t+2 in flight (stage->wait dist ~2 iters).
//    Slot reuse: (t+2)%3 != t%3; old readers 1 barrier upstream. Tail: t=30
//    -> vmcnt(0).
//  * __launch_bounds__(256,3) + 48 KiB -> 3 blocks/CU co-residency (m114
//    cross-block overlap of MFMA / ds_read / staging).
//  * mt-fast within XCD: concurrent set = A 4MB + B 1.5MB (was 7MB).
// MODE 0: QKV epilogue (K/V bf16, R sigmoid bf16). MODE 1: fp32 store.
template <int MODE, int NT>
__global__ __launch_bounds__(256, 3) void gemm128(
    const unsigned short* __restrict__ A,
    const unsigned short* __restrict__ Bw,
    unsigned short* __restrict__ oK, unsigned short* __restrict__ oV,
    unsigned short* __restrict__ oR, float* __restrict__ oF)
{
    __shared__ char sh[49152];               // 3 slots x [A 8KB | B 8KB]

    const int tid  = threadIdx.x;
    const int wave = tid >> 6;
    const int lane = tid & 63;
    const int wm   = wave >> 1;      // 0..1 (M half)
    const int wn   = wave & 1;       // 0..1 (N half)
    const int lrow = lane & 15;
    const int koct = lane >> 4;      // 0..3

    // swizzled frag read offsets; (row>>1)&3 is invariant in mi*16 steps
    const int arow = wm * 64 + lrow;
    const int ao = arow * 64 + ((koct * 16) ^ (((arow >> 1) & 3) << 4));
    const int brow = wn * 64 + lrow;
    const int bo = brow * 64 + ((koct * 16) ^ (((brow >> 1) & 3) << 4));

    // stage offsets: LDS dest linear, global source pre-swizzled.
    // dest d0=tid*16 -> row tid>>2, col (tid&3)*16; slot key ((tid>>3)&3),
    // identical for row+64 (chunk 1).
    const int sc = ((tid & 3) * 16) ^ (((tid >> 3) & 3) << 4);
    const int s0 = (tid >> 2) * GK2 + sc;
    const int s1 = s0 + 64 * GK2;
    const int d0 = tid * 16;
    const int d1 = 4096 + tid * 16;

    // XCD swizzle, mt-fast within XCD (16 mt per XCD slice)
    const int bid = blockIdx.x;
    const int xcd = bid & 7;
    const int idx = bid >> 3;
    const int mt  = xcd * 16 + (idx & 15);
    const int nt  = idx >> 4;
    const size_t row0 = (size_t)mt * 128;
    const size_t col0 = (size_t)nt * 128;

    const char* gA = (const char*)A  + row0 * GK2;
    const char* gB = (const char*)Bw + col0 * GK2;

    // stage tile tt (A and B, 4 gloads/thread) into slot tt%3
    auto stage = [&](int tt) {
        if (tt >= NK32) return;
        char* lb = sh + (tt % 3) * 16384;
        const char* ga = gA + tt * 64;
        const char* gb = gB + tt * 64;
        gload_lds16(ga + s0, lb + d0);
        gload_lds16(ga + s1, lb + d1);
        gload_lds16(gb + s0, lb + 8192 + d0);
        gload_lds16(gb + s1, lb + 8192 + d1);
    };

    // prologue: tiles 0,1 staged; tile0 resident (tile1's 4 in flight)
    stage(0); stage(1);
    asm volatile("s_waitcnt vmcnt(4)" ::: "memory");
    __builtin_amdgcn_s_barrier();

    f32x4 acc[4][4] = {};
    bf16x8 af[4], bf_[4];

    for (int t = 0; t < NK32; ++t) {
        stage(t + 2);                        // depth-2 prefetch
        const char* ab = sh + (t % 3) * 16384 + ao;
        const char* bb = sh + (t % 3) * 16384 + 8192 + bo;
#pragma unroll
        for (int mi = 0; mi < 4; ++mi) af[mi]  = *(const bf16x8*)(ab + mi * 1024);
#pragma unroll
        for (int ni = 0; ni < 4; ++ni) bf_[ni] = *(const bf16x8*)(bb + ni * 1024);
        __builtin_amdgcn_s_setprio(1);
#pragma unroll
        for (int mi = 0; mi < 4; ++mi)
#pragma unroll
            for (int ni = 0; ni < 4; ++ni)
                acc[mi][ni] = __builtin_amdgcn_mfma_f32_16x16x32_bf16(af[mi], bf_[ni], acc[mi][ni], 0, 0, 0);
        __builtin_amdgcn_s_setprio(0);
        if (t <= 29)      asm volatile("s_waitcnt vmcnt(4)" ::: "memory"); // t+1 resident
        else if (t == 30) asm volatile("s_waitcnt vmcnt(0)" ::: "memory"); // tile31 resident
        __builtin_amdgcn_s_barrier();
    }

    // ---- epilogue: C/D frag layout col=lane&15, row=(lane>>4)*4+j
    const int crow = (lane >> 4) * 4;
    const int ccol = lane & 15;
    if (MODE == 1) {
#pragma unroll
        for (int mi = 0; mi < 4; ++mi)
#pragma unroll
            for (int ni = 0; ni < 4; ++ni) {
                size_t gr = row0 + wm * 64 + mi * 16 + crow;
                size_t gc = col0 + wn * 64 + ni * 16 + ccol;
#pragma unroll
                for (int j = 0; j < 4; ++j)
                    oF[(gr + j) * 1024 + gc] = acc[mi][ni][j];
            }
    } else {
        const int region = nt >> 3;  // 0=K, 1=V, 2=R  (24 nt: 8 per region)
        unsigned short* dst = (region == 0) ? oK : ((region == 1) ? oV : oR);
        const size_t cb0 = (size_t)(nt & 7) * 128;
#pragma unroll
        for (int mi = 0; mi < 4; ++mi)
#pragma unroll
            for (int ni = 0; ni < 4; ++ni) {
                size_t gr = row0 + wm * 64 + mi * 16 + crow;
                size_t gc = cb0 + wn * 64 + ni * 16 + ccol;
#pragma unroll
                for (int j = 0; j < 4; ++j) {
                    float val = acc[mi][ni][j];
                    if (region == 2) val = 1.0f / (1.0f + __expf(-val));
                    dst[(gr + j) * 1024 + gc] = f2bf(val);
                }
            }
    }
}

// ---------------- WKV segmented scan (bf16 k,v,r) ----------------
__global__ __launch_bounds__(256) void wkv_phase1(
    const unsigned short* __restrict__ kf, const unsigned short* __restrict__ vf,
    const float* __restrict__ td,
    float* __restrict__ segA, float* __restrict__ segB, float* __restrict__ segP)
{
    const int tid  = blockIdx.x * 256 + threadIdx.x;
    const int lane = tid & 63;
    const int wg   = tid >> 6;
    const int cg   = wg & 63;
    const int s    = wg >> 6;
    const int q    = cg * 64 + lane;
    const int b    = q >> 10;
    const int c    = q & (CDIM - 1);

    const float w = __expf(td[c]);

    float aa = 0.0f, bb = 0.0f, pp = -1e38f;
    size_t idx = (size_t)b * TDIM * CDIM + (size_t)(s * LSEG) * CDIM + c;
#pragma unroll 4
    for (int i = 0; i < LSEG; ++i, idx += CDIM) {
        float kt = bf2f(kf[idx]);
        float vt = bf2f(vf[idx]);
        float ww2 = pp - w;
        float p2  = fmaxf(ww2, kt);
        float e1  = __expf(ww2 - p2);
        float e2  = __expf(kt - p2);
        aa = e1 * aa + e2 * vt;
        bb = e1 * bb + e2;
        pp = p2;
    }
    segA[s * NCH + q] = aa;
    segB[s * NCH + q] = bb;
    segP[s * NCH + q] = pp;
}

__global__ __launch_bounds__(256) void wkv_phase2(
    const float* __restrict__ segA, const float* __restrict__ segB, const float* __restrict__ segP,
    const float* __restrict__ td,
    const float* __restrict__ aa0, const float* __restrict__ bb0, const float* __restrict__ pp0,
    float* __restrict__ preA, float* __restrict__ preB, float* __restrict__ preP,
    float* __restrict__ stout)
{
    const int tid = blockIdx.x * 256 + threadIdx.x;   // 0..NCH-1
    const int c = tid & (CDIM - 1);
    const float w  = __expf(td[c]);
    const float Lw = (float)LSEG * w;

    float aa = aa0[tid], bb = bb0[tid], pp = pp0[tid];
    for (int s = 0; s < SSEG; ++s) {
        preA[s * NCH + tid] = aa;
        preB[s * NCH + tid] = bb;
        preP[s * NCH + tid] = pp;
        float al = segA[s * NCH + tid];
        float bl = segB[s * NCH + tid];
        float pl = segP[s * NCH + tid];
        float ppd = pp - Lw;
        float p  = fmaxf(ppd, pl);
        float e1 = __expf(ppd - p);
        float e2 = __expf(pl - p);
        aa = e1 * aa + e2 * al;
        bb = e1 * bb + e2 * bl;
        pp = p;
    }
    stout[tid]           = aa;
    stout[NCH + tid]     = bb;
    stout[2 * NCH + tid] = pp;
}

__global__ __launch_bounds__(256) void wkv_phase3(
    const unsigned short* __restrict__ kf, const unsigned short* __restrict__ vf,
    const unsigned short* __restrict__ rb,
    const float* __restrict__ td, const float* __restrict__ tf,
    const float* __restrict__ preA, const float* __restrict__ preB, const float* __restrict__ preP,
    unsigned short* __restrict__ rwkvb)
{
    const int tid  = blockIdx.x * 256 + threadIdx.x;
    const int lane = tid & 63;
    const int wg   = tid >> 6;
    const int cg   = wg & 63;
    const int s    = wg >> 6;
    const int q    = cg * 64 + lane;
    const int b    = q >> 10;
    const int c    = q & (CDIM - 1);

    const float w = __expf(td[c]);
    const float u = tf[c];

    float aa = preA[s * NCH + q];
    float bb = preB[s * NCH + q];
    float pp = preP[s * NCH + q];

    size_t idx = (size_t)b * TDIM * CDIM + (size_t)(s * LSEG) * CDIM + c;
#pragma unroll 4
    for (int i = 0; i < LSEG; ++i, idx += CDIM) {
        float kt = bf2f(kf[idx]);
        float vt = bf2f(vf[idx]);
        float rt = bf2f(rb[idx]);
        float ww = u + kt;
        float p  = fmaxf(pp, ww);
        float e1 = __expf(pp - p);
        float e2 = __expf(ww - p);
        float wkv = (e1 * aa + e2 * vt) / (e1 * bb + e2);
        rwkvb[idx] = f2bf(rt * wkv);
        float ww2 = pp - w;
        float p2  = fmaxf(ww2, kt);
        float e1b = __expf(ww2 - p2);
        float e2b = __expf(kt - p2);
        aa = e1b * aa + e2b * vt;
        bb = e1b * bb + e2b;
        pp = p2;
    }
}

extern "C" void kernel_launch(void* const* d_in, const int* in_sizes, int n_in,
                              void* d_out, int out_size, void* d_ws, size_t ws_size,
                              hipStream_t stream) {
    const float* x   = (const float*)d_in[0];
    const float* kw  = (const float*)d_in[1];
    const float* vw  = (const float*)d_in[2];
    const float* rw  = (const float*)d_in[3];
    const float* ow  = (const float*)d_in[4];
    const float* td  = (const float*)d_in[5];
    const float* tf  = (const float*)d_in[6];
    const float* aa0 = (const float*)d_in[7];
    const float* bb0 = (const float*)d_in[8];
    const float* pp0 = (const float*)d_in[9];
    float* out = (float*)d_out;

    char* ws = (char*)d_ws;
    unsigned short* wf    = (unsigned short*)(ws);               //  6,291,456 B  [3072][1024] bf16
    unsigned short* owb   = (unsigned short*)(ws + 6291456);     //  2,097,152 B
    unsigned short* xb    = (unsigned short*)(ws + 8388608);     // 33,554,432 B
    unsigned short* kfb   = (unsigned short*)(ws + 41943040);    // 33,554,432 B
    unsigned short* vfb   = (unsigned short*)(ws + 75497472);    // 33,554,432 B
    unsigned short* rbb   = (unsigned short*)(ws + 109051904);   // 33,554,432 B
    unsigned short* rwkvb = (unsigned short*)(ws + 142606336);   // 33,554,432 B
    float* segA = (float*)(ws + 176160768);
    float* segB = (float*)(ws + 177209344);
    float* segP = (float*)(ws + 178257920);
    float* preA = (float*)(ws + 179306496);
    float* preB = (float*)(ws + 180355072);
    float* preP = (float*)(ws + 181403648);

    // all casts in one launch
    castall<<<20480, 256, 0, stream>>>(x, kw, vw, rw, ow, xb, wf, owb);

    // fused QKV projection: [16384,1024] x [3072,1024]^T, 128x128 tiles,
    // 8 XCD * 16 mt * 24 nt = 3072 blocks, 3 blocks/CU
    gemm128<0, 24><<<3072, 256, 0, stream>>>(xb, wf, kfb, vfb, rbb, nullptr);

    // segmented WKV scan
    wkv_phase1<<<NCH * SSEG / 256, 256, 0, stream>>>(kfb, vfb, td, segA, segB, segP);
    wkv_phase2<<<NCH / 256, 256, 0, stream>>>(segA, segB, segP, td, aa0, bb0, pp0,
                                              preA, preB, preP, out + (size_t)MDIM * CDIM);
    wkv_phase3<<<NCH * SSEG / 256, 256, 0, stream>>>(kfb, vfb, rbb, td, tf,
                                                     preA, preB, preP, rwkvb);

    // output projection: [16384,1024] x [1024,1024]^T -> fp32 d_out,
    // 8 * 16 * 8 = 1024 blocks
    gemm128<1, 8><<<1024, 256, 0, stream>>>(rwkvb, owb, nullptr, nullptr, nullptr, out);
}

// Round 15
// 218.696 us; speedup vs baseline: 1.1320x; 1.0978x over previous
//
#include <hip/hip_runtime.h>
#include <stdint.h>

#define BDIM 4
#define TDIM 4096
#define CDIM 1024
#define MDIM (BDIM * TDIM) // 16384
#define SSEG 64            // segments along T
#define LSEG 64            // steps per segment
#define NCH  (BDIM * CDIM) // 4096 channels

#define GK   1024          // GEMM K
#define GK2  2048          // K row stride in bytes (bf16)
#define NTK  16            // K-tiles of 64

typedef __attribute__((ext_vector_type(8))) short bf16x8;
typedef __attribute__((ext_vector_type(4))) float f32x4;

__device__ __forceinline__ unsigned short f2bf(float f) {
    unsigned u = __builtin_bit_cast(unsigned, f);
    u = u + 0x7fffu + ((u >> 16) & 1u); // RNE
    return (unsigned short)(u >> 16);
}
__device__ __forceinline__ float bf2f(unsigned short h) {
    unsigned u = ((unsigned)h) << 16;
    return __builtin_bit_cast(float, u);
}

typedef __attribute__((address_space(1))) const unsigned int g_u32;
typedef __attribute__((address_space(3))) unsigned int l_u32;
__device__ __forceinline__ void gload_lds16(const void* g, void* l) {
    __builtin_amdgcn_global_load_lds((g_u32*)g, (l_u32*)l, 16, 0, 0);
}

// ---------------- all fp32 -> bf16 casts in ONE launch ----------------
__global__ void castall(const float* __restrict__ x,
                        const float* __restrict__ kw, const float* __restrict__ vw,
                        const float* __restrict__ rw, const float* __restrict__ ow,
                        unsigned short* __restrict__ xb,
                        unsigned short* __restrict__ wf, unsigned short* __restrict__ owb) {
    int i = blockIdx.x * 256 + threadIdx.x;
    const float* s;
    unsigned short* d;
    int j;
    if (i < 4194304) {                       // x
        s = x; d = xb; j = i;
    } else {
        int k = i - 4194304;
        int m = k >> 18; j = k & 262143;     // which weight
        s = (m == 0) ? kw : (m == 1) ? vw : (m == 2) ? rw : ow;
        d = (m < 3) ? (wf + (size_t)m * 1048576) : owb;
    }
    float4 f = ((const float4*)s)[j];
    ushort4 o;
    o.x = f2bf(f.x); o.y = f2bf(f.y); o.z = f2bf(f.z); o.w = f2bf(f.w);
    ((ushort4*)d)[j] = o;
}

// ---------------- 256x256 bf16 GEMM, 2 merged phases per K-tile -------------
// Best measured configuration (round 10, 220.4 us total, QKV 123.5 us /
// ~838 TF, 0 bank conflicts). 16x16x32 MFMA, XOR swizzle both-sides, counted
// vmcnt, intrinsic barriers, L2-locality XCD swizzle (disjoint A-slice per
// XCD, nt-fast). Per K-tile: 4 barriers + 2 vmcnt(4) for 64 MFMA/wave.
//  P0: read bf_[0..3] + af[4..7] (16 ds_read); stage B0,B1(t+1); barrier;
//      32 MFMA (mh0 x all n); vmcnt(4) [A(t+1) resident]; barrier.
//  P1: prefetch af[0..3] of t+1 (other slot); stage A0,A1(t+2); barrier;
//      32 MFMA (mh1 x all n); vmcnt(4) [B(t+1) resident]; barrier.
// Hazards: every stage->read / read->overwrite pair >= 1 barrier apart.
// Tail: t=14 -> (4,0); t=15 no stages/waits.
// MODE 0: fused QKV epilogue -> oK/oV(bf16), oR(sigmoid,bf16). MODE 1: fp32.
template <int MODE, int NT>
__global__ __launch_bounds__(512, 2) void gemm256(
    const unsigned short* __restrict__ A,
    const unsigned short* __restrict__ Bw,
    unsigned short* __restrict__ oK, unsigned short* __restrict__ oV,
    unsigned short* __restrict__ oR, float* __restrict__ oF)
{
    extern __shared__ char sh[];
    char* shA = sh;             // 2 slots x 2 halves x 16384 B
    char* shB = sh + 65536;

    const int tid  = threadIdx.x;
    const int wave = tid >> 6;
    const int lane = tid & 63;
    const int wm   = wave >> 2;      // 0..1 (M half)
    const int wn   = wave & 3;       // 0..3 (N quarter)
    const int lrow = lane & 15;
    const int koct = lane >> 4;      // 0..3

    // per-thread-constant swizzled k-offsets for LDS reads
    const int kb0 = (koct * 16) ^ ((lrow & 7) << 4);
    const int kb1 = kb0 ^ 64;

    // per-thread-constant stage offsets (2 chunks of 16B per stage call)
    const int sr0  = tid >> 3;                 // row of chunk 0 (0..63)
    const int sc0  = ((tid & 7) * 16) ^ ((sr0 & 7) << 4);
    const int sr1  = (512 + tid) >> 3;         // row of chunk 1 (64..127)
    const int sc1  = ((tid & 7) * 16) ^ ((sr1 & 7) << 4);
    const int sd0  = tid * 16;
    const int sd1  = 8192 + tid * 16;

    // L2-locality XCD swizzle (grid = 8 * 8 * NT blocks)
    const int bid = blockIdx.x;
    const int xcd = bid & 7;
    const int idx = bid >> 3;
    const int mt  = xcd * 8 + idx / NT;  // disjoint A-slice per XCD
    const int nt  = idx % NT;            // nt-fast: A panel L2-reused
    const size_t row0 = (size_t)mt * 256;
    const size_t col0 = (size_t)nt * 256;

    const char* gA = (const char*)A  + row0 * GK2;
    const char* gB = (const char*)Bw + col0 * GK2;

    // stage one half-tile of tile tt; part: 0=A h0, 1=A h1, 2=B h0, 3=B h1
    auto stage = [&](int tt, int part) {
        if (tt >= NTK) return;
        int slot = tt & 1;
        int isA  = (part < 2) ? 1 : 0;
        int half = part & 1;
        const char* gbase = (isA ? gA : gB) + (size_t)half * 128 * GK2 + tt * 128;
        char* lbase = (isA ? shA : shB) + (slot * 2 + half) * 16384;
        gload_lds16(gbase + (size_t)sr0 * GK2 + sc0, lbase + sd0);
        gload_lds16(gbase + (size_t)sr1 * GK2 + sc1, lbase + sd1);
    };

    // prologue: tile0 (A0,A1,B0,B1) + tile1 (A0,A1) = 6 halves (12 loads)
    stage(0, 0); stage(0, 1); stage(0, 2); stage(0, 3);
    stage(1, 0); stage(1, 1);
    asm volatile("s_waitcnt vmcnt(4)" ::: "memory");   // tile0 fully resident
    __builtin_amdgcn_s_barrier();

    f32x4 acc[8][4] = {};
    bf16x8 af[8][2], bf_[4][2];

    // pre-read af[0..3] of tile 0 (slot 0)
    {
        const char* ab0 = shA + wm * 16384 + lrow * 128;
#pragma unroll
        for (int mi = 0; mi < 4; ++mi) {
            af[mi][0] = *(const bf16x8*)(ab0 + mi * 2048 + kb0);
            af[mi][1] = *(const bf16x8*)(ab0 + mi * 2048 + kb1);
        }
    }

    for (int t = 0; t < NTK; ++t) {
        const int slot  = t & 1;
        const char* ab  = shA + (slot * 2 + wm) * 16384 + lrow * 128;
        const char* bb  = shB + (slot * 2 + (wn >> 1)) * 16384 + ((wn & 1) * 64 + lrow) * 128;
        const char* abN = shA + (((t + 1) & 1) * 2 + wm) * 16384 + lrow * 128;

        // ==== P0: read bf_[0..3] + af[4..7]; stage B0,B1(t+1); 32 MFMA (mh0)
#pragma unroll
        for (int ni = 0; ni < 4; ++ni) {
            bf_[ni][0] = *(const bf16x8*)(bb + ni * 2048 + kb0);
            bf_[ni][1] = *(const bf16x8*)(bb + ni * 2048 + kb1);
        }
#pragma unroll
        for (int mi = 4; mi < 8; ++mi) {
            af[mi][0] = *(const bf16x8*)(ab + mi * 2048 + kb0);
            af[mi][1] = *(const bf16x8*)(ab + mi * 2048 + kb1);
        }
        stage(t + 1, 2);
        stage(t + 1, 3);
        __builtin_amdgcn_s_barrier();
        __builtin_amdgcn_s_setprio(1);
#pragma unroll
        for (int a = 0; a < 4; ++a)
#pragma unroll
            for (int b = 0; b < 4; ++b)
#pragma unroll
                for (int ks = 0; ks < 2; ++ks)
                    acc[a][b] = __builtin_amdgcn_mfma_f32_16x16x32_bf16(af[a][ks], bf_[b][ks], acc[a][b], 0, 0, 0);
        __builtin_amdgcn_s_setprio(0);
        if (t <= 14)      asm volatile("s_waitcnt vmcnt(4)" ::: "memory"); // A(t+1) resident
        __builtin_amdgcn_s_barrier();

        // ==== P1: prefetch af[0..3](t+1); stage A0,A1(t+2); 32 MFMA (mh1)
        if (t + 1 < NTK) {
#pragma unroll
            for (int mi = 0; mi < 4; ++mi) {
                af[mi][0] = *(const bf16x8*)(abN + mi * 2048 + kb0);
                af[mi][1] = *(const bf16x8*)(abN + mi * 2048 + kb1);
            }
        }
        stage(t + 2, 0);
        stage(t + 2, 1);
        __builtin_amdgcn_s_barrier();
        __builtin_amdgcn_s_setprio(1);
#pragma unroll
        for (int a = 0; a < 4; ++a)
#pragma unroll
            for (int b = 0; b < 4; ++b)
#pragma unroll
                for (int ks = 0; ks < 2; ++ks)
                    acc[4 + a][b] = __builtin_amdgcn_mfma_f32_16x16x32_bf16(af[4 + a][ks], bf_[b][ks], acc[4 + a][b], 0, 0, 0);
        __builtin_amdgcn_s_setprio(0);
        if (t <= 13)      asm volatile("s_waitcnt vmcnt(4)" ::: "memory"); // B(t+1) resident
        else if (t == 14) asm volatile("s_waitcnt vmcnt(0)" ::: "memory");
        __builtin_amdgcn_s_barrier();
    }

    // ---- epilogue: C/D frag layout col=lane&15, row=(lane>>4)*4+j
    const int crow = (lane >> 4) * 4;
    const int ccol = lane & 15;
    if (MODE == 1) {
#pragma unroll
        for (int mi = 0; mi < 8; ++mi)
#pragma unroll
            for (int ni = 0; ni < 4; ++ni) {
                size_t gr = row0 + wm * 128 + mi * 16 + crow;
                size_t gc = col0 + wn * 64 + ni * 16 + ccol;
#pragma unroll
                for (int j = 0; j < 4; ++j)
                    oF[(gr + j) * 1024 + gc] = acc[mi][ni][j];
            }
    } else {
        const int region = nt >> 2;  // 0=K, 1=V, 2=R
        unsigned short* dst = (region == 0) ? oK : ((region == 1) ? oV : oR);
        const size_t cb0 = (size_t)(nt & 3) * 256;
#pragma unroll
        for (int mi = 0; mi < 8; ++mi)
#pragma unroll
            for (int ni = 0; ni < 4; ++ni) {
                size_t gr = row0 + wm * 128 + mi * 16 + crow;
                size_t gc = cb0 + wn * 64 + ni * 16 + ccol;
#pragma unroll
                for (int j = 0; j < 4; ++j) {
                    float val = acc[mi][ni][j];
                    if (region == 2) val = 1.0f / (1.0f + __expf(-val));
                    dst[(gr + j) * 1024 + gc] = f2bf(val);
                }
            }
    }
}

// ---------------- WKV segmented scan (bf16 k,v,r) ----------------
__global__ __launch_bounds__(256) void wkv_phase1(
    const unsigned short* __restrict__ kf, const unsigned short* __restrict__ vf,
    const float* __restrict__ td,
    float* __restrict__ segA, float* __restrict__ segB, float* __restrict__ segP)
{
    const int tid  = blockIdx.x * 256 + threadIdx.x;
    const int lane = tid & 63;
    const int wg   = tid >> 6;
    const int cg   = wg & 63;
    const int s    = wg >> 6;
    const int q    = cg * 64 + lane;
    const int b    = q >> 10;
    const int c    = q & (CDIM - 1);

    const float w = __expf(td[c]);

    float aa = 0.0f, bb = 0.0f, pp = -1e38f;
    size_t idx = (size_t)b * TDIM * CDIM + (size_t)(s * LSEG) * CDIM + c;
#pragma unroll 4
    for (int i = 0; i < LSEG; ++i, idx += CDIM) {
        float kt = bf2f(kf[idx]);
        float vt = bf2f(vf[idx]);
        float ww2 = pp - w;
        float p2  = fmaxf(ww2, kt);
        float e1  = __expf(ww2 - p2);
        float e2  = __expf(kt - p2);
        aa = e1 * aa + e2 * vt;
        bb = e1 * bb + e2;
        pp = p2;
    }
    segA[s * NCH + q] = aa;
    segB[s * NCH + q] = bb;
    segP[s * NCH + q] = pp;
}

__global__ __launch_bounds__(256) void wkv_phase2(
    const float* __restrict__ segA, const float* __restrict__ segB, const float* __restrict__ segP,
    const float* __restrict__ td,
    const float* __restrict__ aa0, const float* __restrict__ bb0, const float* __restrict__ pp0,
    float* __restrict__ preA, float* __restrict__ preB, float* __restrict__ preP,
    float* __restrict__ stout)
{
    const int tid = blockIdx.x * 256 + threadIdx.x;   // 0..NCH-1
    const int c = tid & (CDIM - 1);
    const float w  = __expf(td[c]);
    const float Lw = (float)LSEG * w;

    float aa = aa0[tid], bb = bb0[tid], pp = pp0[tid];
    for (int s = 0; s < SSEG; ++s) {
        preA[s * NCH + tid] = aa;
        preB[s * NCH + tid] = bb;
        preP[s * NCH + tid] = pp;
        float al = segA[s * NCH + tid];
        float bl = segB[s * NCH + tid];
        float pl = segP[s * NCH + tid];
        float ppd = pp - Lw;
        float p  = fmaxf(ppd, pl);
        float e1 = __expf(ppd - p);
        float e2 = __expf(pl - p);
        aa = e1 * aa + e2 * al;
        bb = e1 * bb + e2 * bl;
        pp = p;
    }
    stout[tid]           = aa;
    stout[NCH + tid]     = bb;
    stout[2 * NCH + tid] = pp;
}

__global__ __launch_bounds__(256) void wkv_phase3(
    const unsigned short* __restrict__ kf, const unsigned short* __restrict__ vf,
    const unsigned short* __restrict__ rb,
    const float* __restrict__ td, const float* __restrict__ tf,
    const float* __restrict__ preA, const float* __restrict__ preB, const float* __restrict__ preP,
    unsigned short* __restrict__ rwkvb)
{
    const int tid  = blockIdx.x * 256 + threadIdx.x;
    const int lane = tid & 63;
    const int wg   = tid >> 6;
    const int cg   = wg & 63;
    const int s    = wg >> 6;
    const int q    = cg * 64 + lane;
    const int b    = q >> 10;
    const int c    = q & (CDIM - 1);

    const float w = __expf(td[c]);
    const float u = tf[c];

    float aa = preA[s * NCH + q];
    float bb = preB[s * NCH + q];
    float pp = preP[s * NCH + q];

    size_t idx = (size_t)b * TDIM * CDIM + (size_t)(s * LSEG) * CDIM + c;
#pragma unroll 4
    for (int i = 0; i < LSEG; ++i, idx += CDIM) {
        float kt = bf2f(kf[idx]);
        float vt = bf2f(vf[idx]);
        float rt = bf2f(rb[idx]);
        float ww = u + kt;
        float p  = fmaxf(pp, ww);
        float e1 = __expf(pp - p);
        float e2 = __expf(ww - p);
        float wkv = (e1 * aa + e2 * vt) / (e1 * bb + e2);
        rwkvb[idx] = f2bf(rt * wkv);
        float ww2 = pp - w;
        float p2  = fmaxf(ww2, kt);
        float e1b = __expf(ww2 - p2);
        float e2b = __expf(kt - p2);
        aa = e1b * aa + e2b * vt;
        bb = e1b * bb + e2b;
        pp = p2;
    }
}

extern "C" void kernel_launch(void* const* d_in, const int* in_sizes, int n_in,
                              void* d_out, int out_size, void* d_ws, size_t ws_size,
                              hipStream_t stream) {
    const float* x   = (const float*)d_in[0];
    const float* kw  = (const float*)d_in[1];
    const float* vw  = (const float*)d_in[2];
    const float* rw  = (const float*)d_in[3];
    const float* ow  = (const float*)d_in[4];
    const float* td  = (const float*)d_in[5];
    const float* tf  = (const float*)d_in[6];
    const float* aa0 = (const float*)d_in[7];
    const float* bb0 = (const float*)d_in[8];
    const float* pp0 = (const float*)d_in[9];
    float* out = (float*)d_out;

    char* ws = (char*)d_ws;
    unsigned short* wf    = (unsigned short*)(ws);               //  6,291,456 B  [3072][1024] bf16
    unsigned short* owb   = (unsigned short*)(ws + 6291456);     //  2,097,152 B
    unsigned short* xb    = (unsigned short*)(ws + 8388608);     // 33,554,432 B
    unsigned short* kfb   = (unsigned short*)(ws + 41943040);    // 33,554,432 B
    unsigned short* vfb   = (unsigned short*)(ws + 75497472);    // 33,554,432 B
    unsigned short* rbb   = (unsigned short*)(ws + 109051904);   // 33,554,432 B
    unsigned short* rwkvb = (unsigned short*)(ws + 142606336);   // 33,554,432 B
    float* segA = (float*)(ws + 176160768);
    float* segB = (float*)(ws + 177209344);
    float* segP = (float*)(ws + 178257920);
    float* preA = (float*)(ws + 179306496);
    float* preB = (float*)(ws + 180355072);
    float* preP = (float*)(ws + 181403648);

    hipFuncSetAttribute((const void*)(gemm256<0, 12>), hipFuncAttributeMaxDynamicSharedMemorySize, 131072);
    hipFuncSetAttribute((const void*)(gemm256<1, 4>),  hipFuncAttributeMaxDynamicSharedMemorySize, 131072);

    // all casts in one launch: 4M (x) + 1M (weights) float4 chunks
    castall<<<20480, 256, 0, stream>>>(x, kw, vw, rw, ow, xb, wf, owb);

    // fused QKV projection: [16384,1024] x [3072,1024]^T, 768 blocks
    gemm256<0, 12><<<768, 512, 131072, stream>>>(xb, wf, kfb, vfb, rbb, nullptr);

    // segmented WKV scan
    wkv_phase1<<<NCH * SSEG / 256, 256, 0, stream>>>(kfb, vfb, td, segA, segB, segP);
    wkv_phase2<<<NCH / 256, 256, 0, stream>>>(segA, segB, segP, td, aa0, bb0, pp0,
                                              preA, preB, preP, out + (size_t)MDIM * CDIM);
    wkv_phase3<<<NCH * SSEG / 256, 256, 0, stream>>>(kfb, vfb, rbb, td, tf,
                                                     preA, preB, preP, rwkvb);

    // output projection: [16384,1024] x [1024,1024]^T -> fp32 d_out, 256 blocks
    gemm256<1, 4><<<256, 512, 131072, stream>>>(rwkvb, owb, nullptr, nullptr, nullptr, out);
}